// Round 2
// baseline (289.452 us; speedup 1.0000x reference)
//
#include <hip/hip_runtime.h>

#define BATCH 2
#define NVIEW 4
#define NJOINT 24
#define HM 96
#define VOLD 48
#define NVOX (VOLD*VOLD*VOLD)   // 110592

// thread = one (x,y) column segment of ZSEG consecutive z values
#define ZSEG 8
#define NSEG (VOLD/ZSEG)            // 6
#define NCOL (VOLD*VOLD*NSEG)       // 13824 columns
#define TPB 256
#define NCHUNK (NCOL/TPB)           // 54 blocks per (b,j)

// acc layout: [B*J][4] = {sum_w, sum_wx, sum_wy, sum_wz}
__global__ __launch_bounds__(TPB) void vol_acc_kernel(
    const float* __restrict__ hm,   // (B,V,J,96,96)
    const float* __restrict__ pm,   // (B,V,3,4)
    const float* __restrict__ cv,   // (B,48,48,48,3)
    float* __restrict__ acc)
{
    __shared__ float Zs[VOLD];

    const int bj  = blockIdx.y;
    const int b   = bj / NJOINT;
    const int j   = bj - b * NJOINT;
    const int tid = threadIdx.x;

    const float* cvb = cv + (size_t)b * NVOX * 3;
    if (tid < VOLD) Zs[tid] = cvb[tid * 3 + 2];     // cv[b,0,0,z,2]

    // projection matrices — uniform per block -> SGPRs
    float M[NVIEW][12];
#pragma unroll
    for (int v = 0; v < NVIEW; ++v)
#pragma unroll
        for (int k = 0; k < 12; ++k) M[v][k] = pm[(b * NVIEW + v) * 12 + k];

    __syncthreads();

    const int col = blockIdx.x * TPB + tid;
    const int xy  = col / NSEG;
    const int s   = col - xy * NSEG;
    const int x   = xy / VOLD;
    const int y   = xy - x * VOLD;
    const int z0  = s * ZSEG;

    // separable grid: X depends only on x, Y only on y (grid + per-batch offset)
    const float X = cvb[(size_t)x * (VOLD * VOLD) * 3 + 0];   // cv[b,x,0,0,0]
    const float Y = cvb[(size_t)y * VOLD * 3 + 1];            // cv[b,0,y,0,1]

    // per-view constants: p = c + Z * m_col2
    float cx[NVIEW], cy[NVIEW], cz[NVIEW];
#pragma unroll
    for (int v = 0; v < NVIEW; ++v) {
        cx[v] = fmaf(M[v][1], Y, fmaf(M[v][0], X, M[v][3]));
        cy[v] = fmaf(M[v][5], Y, fmaf(M[v][4], X, M[v][7]));
        cz[v] = fmaf(M[v][9], Y, fmaf(M[v][8], X, M[v][11]));
    }

    const float* img0 = hm + ((size_t)(b * NVIEW) * NJOINT + j) * (HM * HM);

    float sw = 0.f, swz = 0.f;

#pragma unroll
    for (int k = 0; k < ZSEG; ++k) {
        const float Z = Zs[z0 + k];
        float vol = 0.f;
#pragma unroll
        for (int v = 0; v < NVIEW; ++v) {
            const float pz  = fmaf(Z, M[v][10], cz[v]);
            const float pzc = pz > 0.f ? pz : 1.0f;
            const float inv = __builtin_amdgcn_rcpf(pzc) * (95.0f / 96.0f);
            const float ix  = fmaf(Z, M[v][2], cx[v]) * inv;
            const float iy  = fmaf(Z, M[v][6], cy[v]) * inv;

            const float x0f = floorf(ix), y0f = floorf(iy);
            const float wx1 = ix - x0f,  wy1 = iy - y0f;
            const int x0 = (int)x0f, y0 = (int)y0f;
            const int x1 = x0 + 1,   y1 = y0 + 1;

            // fold validity (incl. pz>0) into the weights -> branchless
            const bool vz  = pz > 0.f;
            const float wx0m = ((unsigned)x0 < (unsigned)HM) ? (1.f - wx1) : 0.f;
            const float wx1m = ((unsigned)x1 < (unsigned)HM) ? wx1 : 0.f;
            const float wy0m = (((unsigned)y0 < (unsigned)HM) && vz) ? (1.f - wy1) : 0.f;
            const float wy1m = (((unsigned)y1 < (unsigned)HM) && vz) ? wy1 : 0.f;

            const int xc0 = min(max(x0, 0), HM - 1);
            const int xc1 = min(max(x1, 0), HM - 1);
            const int yc0 = min(max(y0, 0), HM - 1);
            const int yc1 = min(max(y1, 0), HM - 1);

            const float* img = img0 + (size_t)v * (NJOINT * HM * HM);
            const float t00 = img[yc0 * HM + xc0];
            const float t01 = img[yc0 * HM + xc1];
            const float t10 = img[yc1 * HM + xc0];
            const float t11 = img[yc1 * HM + xc1];

            vol += wy0m * fmaf(wx1m, t01, wx0m * t00)
                 + wy1m * fmaf(wx1m, t11, wx0m * t10);
        }
        // vol in [0,4] -> exp safe without max subtraction
        const float w = __expf(vol);
        sw  += w;
        swz  = fmaf(w, Z, swz);
    }

    // per-thread X,Y are constant: sum(w*X) = X*sum(w)
    float r0 = sw, r1 = X * sw, r2 = Y * sw, r3 = swz;

#pragma unroll
    for (int off = 32; off > 0; off >>= 1) {
        r0 += __shfl_down(r0, off);
        r1 += __shfl_down(r1, off);
        r2 += __shfl_down(r2, off);
        r3 += __shfl_down(r3, off);
    }
    if ((tid & 63) == 0) {
        atomicAdd(&acc[bj * 4 + 0], r0);
        atomicAdd(&acc[bj * 4 + 1], r1);
        atomicAdd(&acc[bj * 4 + 2], r2);
        atomicAdd(&acc[bj * 4 + 3], r3);
    }
}

__global__ void finalize_kernel(const float* __restrict__ acc, float* __restrict__ out)
{
    const int i = threadIdx.x;
    if (i < BATCH * NJOINT * 3) {
        const int bj = i / 3;
        const int c  = i - bj * 3;
        out[i] = acc[bj * 4 + 1 + c] / acc[bj * 4 + 0];
    }
}

extern "C" void kernel_launch(void* const* d_in, const int* in_sizes, int n_in,
                              void* d_out, int out_size, void* d_ws, size_t ws_size,
                              hipStream_t stream)
{
    const float* hm = (const float*)d_in[0];
    const float* pm = (const float*)d_in[1];
    const float* cv = (const float*)d_in[2];
    float* out = (float*)d_out;
    float* acc = (float*)d_ws;

    hipMemsetAsync(acc, 0, BATCH * NJOINT * 4 * sizeof(float), stream);

    dim3 grid(NCHUNK, BATCH * NJOINT);
    vol_acc_kernel<<<grid, TPB, 0, stream>>>(hm, pm, cv, acc);
    finalize_kernel<<<1, 192, 0, stream>>>(acc, out);
}

// Round 5
// 145.308 us; speedup vs baseline: 1.9920x; 1.9920x over previous
//
#include <hip/hip_runtime.h>

#define BATCH 2
#define NVIEW 4
#define NJOINT 24
#define HM 96
#define VOLD 48
#define NVOX (VOLD*VOLD*VOLD)      // 110592
#define IMG (HM*HM)                // 9216
#define HMT_OFF 256                // float offset of transposed heatmaps in d_ws (acc uses first 192)
#define RED_STRIDE 260             // LDS row stride (mult of 4 for float4, 260%32=4 spreads banks)

// hm (B,V,J,H,W) -> hmT (B,V,H,W,J): J contiguous so one tap serves all 24 joints
__global__ __launch_bounds__(256) void transpose_kernel(
    const float* __restrict__ hm, float* __restrict__ hmT)
{
    const int o  = blockIdx.x * 256 + threadIdx.x;   // 1,769,472 total = 6912*256 exact
    const int j  = o % NJOINT;
    const int r  = o / NJOINT;                       // bv*9216 + y*96 + x
    const int xy = r % IMG;
    const int bv = r / IMG;
    hmT[o] = hm[(bv * NJOINT + j) * IMG + xy];       // coalesced write, gather read
}

// thread = one voxel, all 24 joints. acc[bj][4] = {sum_w, sum_wx, sum_wy, sum_wz}
__global__ __launch_bounds__(256, 2) void vol_main_kernel(
    const float* __restrict__ hmT,  // (B,V,H,W,J)
    const float* __restrict__ pm,   // (B,V,3,4)
    const float* __restrict__ cv,   // (B,48,48,48,3)
    float* __restrict__ acc)
{
    __shared__ float Xt[VOLD], Yt[VOLD], Zt[VOLD];
    __shared__ float red[NJOINT * RED_STRIDE];       // 24.96 KB
    __shared__ float red2[NJOINT * 4];

    const int tid = threadIdx.x;
    const int gid = blockIdx.x * 256 + tid;          // 864 blocks * 256 = B*NVOX exact
    const int b   = gid / NVOX;                      // blocks never straddle b (110592%256==0)
    const int m   = gid - b * NVOX;
    const int z   = m % VOLD;                        // z fastest -> lanes walk smooth pixel paths
    const int t2  = m / VOLD;
    const int y   = t2 % VOLD;
    const int x   = t2 / VOLD;

    const float* cvb = cv + (size_t)b * NVOX * 3;
    if (tid < VOLD) {   // separable grid: X dep only on x, Y on y, Z on z
        Xt[tid] = cvb[(size_t)tid * (VOLD * VOLD * 3)];
        Yt[tid] = cvb[(size_t)tid * (VOLD * 3) + 1];
        Zt[tid] = cvb[(size_t)tid * 3 + 2];
    }

    float Mv[NVIEW][12];   // uniform per block -> scalar regs
#pragma unroll
    for (int v = 0; v < NVIEW; ++v)
#pragma unroll
        for (int k = 0; k < 12; ++k) Mv[v][k] = pm[(b * NVIEW + v) * 12 + k];

    __syncthreads();

    const float X = Xt[x], Y = Yt[y], Z = Zt[z];

    float vol[NJOINT];
#pragma unroll
    for (int q = 0; q < NJOINT; ++q) vol[q] = 0.f;

#pragma unroll
    for (int v = 0; v < NVIEW; ++v) {
        const float* mv = Mv[v];
        const float pz  = fmaf(mv[8], X, fmaf(mv[9], Y, fmaf(mv[10], Z, mv[11])));
        const float pxn = fmaf(mv[0], X, fmaf(mv[1], Y, fmaf(mv[2],  Z, mv[3])));
        const float pyn = fmaf(mv[4], X, fmaf(mv[5], Y, fmaf(mv[6],  Z, mv[7])));

        const float pzc = pz > 0.f ? pz : 1.0f;
        const float inv = __builtin_amdgcn_rcpf(pzc) * (95.0f / 96.0f);
        const float ix  = pxn * inv;
        const float iy  = pyn * inv;

        const float x0f = floorf(ix), y0f = floorf(iy);
        const float wx1 = ix - x0f,  wy1 = iy - y0f;
        const int x0 = (int)x0f, y0 = (int)y0f;
        const int x1 = x0 + 1,   y1 = y0 + 1;

        const bool vz = pz > 0.f;   // reference zeroes samples with z<=0
        const float wx0m = ((unsigned)x0 < (unsigned)HM) ? (1.f - wx1) : 0.f;
        const float wx1m = ((unsigned)x1 < (unsigned)HM) ? wx1 : 0.f;
        const float wy0m = (((unsigned)y0 < (unsigned)HM) && vz) ? (1.f - wy1) : 0.f;
        const float wy1m = (((unsigned)y1 < (unsigned)HM) && vz) ? wy1 : 0.f;

        const float w00 = wy0m * wx0m, w01 = wy0m * wx1m;
        const float w10 = wy1m * wx0m, w11 = wy1m * wx1m;

        const int xc0 = min(max(x0, 0), HM - 1);
        const int xc1 = min(max(x1, 0), HM - 1);
        const int yc0 = min(max(y0, 0), HM - 1);
        const int yc1 = min(max(y1, 0), HM - 1);

        const float* base = hmT + (size_t)(b * NVIEW + v) * (IMG * NJOINT);
        const float4* p00 = (const float4*)(base + (yc0 * HM + xc0) * NJOINT); // 96B aligned
        const float4* p01 = (const float4*)(base + (yc0 * HM + xc1) * NJOINT);
        const float4* p10 = (const float4*)(base + (yc1 * HM + xc0) * NJOINT);
        const float4* p11 = (const float4*)(base + (yc1 * HM + xc1) * NJOINT);

#pragma unroll
        for (int c4 = 0; c4 < 6; ++c4) {
            const float4 f00 = p00[c4];
            const float4 f01 = p01[c4];
            const float4 f10 = p10[c4];
            const float4 f11 = p11[c4];
            vol[c4*4+0] = fmaf(w00, f00.x, fmaf(w01, f01.x, fmaf(w10, f10.x, fmaf(w11, f11.x, vol[c4*4+0]))));
            vol[c4*4+1] = fmaf(w00, f00.y, fmaf(w01, f01.y, fmaf(w10, f10.y, fmaf(w11, f11.y, vol[c4*4+1]))));
            vol[c4*4+2] = fmaf(w00, f00.z, fmaf(w01, f01.z, fmaf(w10, f10.z, fmaf(w11, f11.z, vol[c4*4+2]))));
            vol[c4*4+3] = fmaf(w00, f00.w, fmaf(w01, f01.w, fmaf(w10, f10.w, fmaf(w11, f11.w, vol[c4*4+3]))));
        }
    }

    // vol in [0,4] -> exp safe without max subtraction; softmax ratio identical
#pragma unroll
    for (int q = 0; q < NJOINT; ++q) vol[q] = __expf(vol[q]);

    // block reduction: 4 passes over components {w, w*X, w*Y, w*Z}
#pragma unroll
    for (int p = 0; p < 4; ++p) {
        const float scale = (p == 0) ? 1.0f : (p == 1) ? X : (p == 2) ? Y : Z;
#pragma unroll
        for (int q = 0; q < NJOINT; ++q)
            red[q * RED_STRIDE + tid] = vol[q] * scale;   // banks (4q+tid)%32: conflict-free
        __syncthreads();

        if (tid < 96) {   // owner (q, seg) sums 64 of the 256 thread values
            const int q = tid % NJOINT, seg = tid / NJOINT;
            const float4* row = (const float4*)&red[q * RED_STRIDE + seg * 64];
            float s = 0.f;
#pragma unroll
            for (int i = 0; i < 16; ++i) {
                const float4 f = row[i];
                s += (f.x + f.y) + (f.z + f.w);
            }
            red2[seg * NJOINT + q] = s;
        }
        __syncthreads();

        if (tid < NJOINT) {
            const float s = (red2[tid] + red2[tid + 24]) + (red2[tid + 48] + red2[tid + 72]);
            atomicAdd(&acc[(b * NJOINT + tid) * 4 + p], s);
        }
        __syncthreads();   // protect red2 before next pass's owner writes
    }
}

__global__ void finalize_kernel(const float* __restrict__ acc, float* __restrict__ out)
{
    const int i = threadIdx.x;
    if (i < BATCH * NJOINT * 3) {
        const int bj = i / 3;
        const int c  = i - bj * 3;
        out[i] = acc[bj * 4 + 1 + c] / acc[bj * 4 + 0];
    }
}

extern "C" void kernel_launch(void* const* d_in, const int* in_sizes, int n_in,
                              void* d_out, int out_size, void* d_ws, size_t ws_size,
                              hipStream_t stream)
{
    const float* hm = (const float*)d_in[0];   // (B,V,J,96,96)
    const float* pm = (const float*)d_in[1];   // (B,V,3,4)
    const float* cv = (const float*)d_in[2];   // (B,48,48,48,3)
    float* out = (float*)d_out;                // (B,J,3)
    float* acc = (float*)d_ws;                 // 192 floats
    float* hmT = (float*)d_ws + HMT_OFF;       // 7.08 MB transposed heatmaps

    hipMemsetAsync(acc, 0, BATCH * NJOINT * 4 * sizeof(float), stream);

    transpose_kernel<<<(BATCH*NVIEW*NJOINT*IMG)/256, 256, 0, stream>>>(hm, hmT);

    vol_main_kernel<<<(BATCH*NVOX)/256, 256, 0, stream>>>(hmT, pm, cv, acc);

    finalize_kernel<<<1, 192, 0, stream>>>(acc, out);
}